// Round 4
// baseline (46.904 us; speedup 1.0000x reference)
//
#include <hip/hip_runtime.h>

// out[b, r, c] = x[b, r, c] - (r >= 2 ? x[b, r-2, c] : 0)
// x: (32, 1, 1024, 1024) float32.
//
// Register-history version: each block owns a 16-row strip of one image.
// 256 threads = 256 float4 columns (1024 floats) of a row. The block walks
// the strip top->bottom; each thread keeps x[r-2], x[r-1] in registers so
// the shifted operand never issues a second HBM read. 16-row strips give
// 2048 blocks (8/CU) for better latency hiding than the 32-row version.

__global__ __launch_bounds__(256) void dir2_diff_kernel(
    const float4* __restrict__ x, float4* __restrict__ out) {
  constexpr int W4 = 256;    // float4s per row
  constexpr int ROWS = 16;   // rows per block strip

  const int img = blockIdx.x >> 6;    // 64 chunks per image
  const int chunk = blockIdx.x & 63;
  const int r0 = chunk * ROWS;
  const int c = threadIdx.x;

  const float4* __restrict__ xb = x + ((size_t)img << 18);  // 1024*256 float4/image
  float4* __restrict__ ob = out + ((size_t)img << 18);

  const float4 zero = make_float4(0.f, 0.f, 0.f, 0.f);
  // History prologue: rows r0-2, r0-1 (zero if out of image).
  float4 s_m2 = (r0 >= 2) ? xb[(r0 - 2) * W4 + c] : zero;
  float4 s_m1 = (r0 >= 1) ? xb[(r0 - 1) * W4 + c] : zero;

  int idx = r0 * W4 + c;
#pragma unroll 8
  for (int r = 0; r < ROWS; ++r, idx += W4) {
    float4 a = xb[idx];
    float4 o;
    o.x = a.x - s_m2.x;
    o.y = a.y - s_m2.y;
    o.z = a.z - s_m2.z;
    o.w = a.w - s_m2.w;
    ob[idx] = o;
    s_m2 = s_m1;
    s_m1 = a;
  }
}

extern "C" void kernel_launch(void* const* d_in, const int* in_sizes, int n_in,
                              void* d_out, int out_size, void* d_ws, size_t ws_size,
                              hipStream_t stream) {
  const float4* x = (const float4*)d_in[0];
  float4* out = (float4*)d_out;
  // 32 images * (1024 rows / 16 rows-per-block) = 2048 blocks
  dir2_diff_kernel<<<2048, 256, 0, stream>>>(x, out);
}

// Round 5
// 45.588 us; speedup vs baseline: 1.0289x; 1.0289x over previous
//
#include <hip/hip_runtime.h>

// out[b, r, c] = x[b, r, c] - (r >= 2 ? x[b, r-2, c] : 0)
// x: (32, 1, 1024, 1024) float32.
//
// Register-history + non-temporal stores: each block owns a 32-row strip of
// one image; each thread keeps x[r-2], x[r-1] in registers (no second HBM
// read for the shifted operand). Output stores use the nt policy so they
// don't allocate in L2/L3 -- the 128 MiB input then stays fully resident in
// the 256 MiB Infinity Cache across graph replays, making reads L3-hits and
// leaving the HBM write stream as the only mandatory traffic.

typedef float f4_t __attribute__((ext_vector_type(4)));

__global__ __launch_bounds__(256) void dir2_diff_kernel(
    const f4_t* __restrict__ x, f4_t* __restrict__ out) {
  constexpr int W4 = 256;    // float4s per row
  constexpr int ROWS = 32;   // rows per block strip

  const int img = blockIdx.x >> 5;    // 32 chunks per image
  const int chunk = blockIdx.x & 31;
  const int r0 = chunk * ROWS;
  const int c = threadIdx.x;

  const f4_t* __restrict__ xb = x + ((size_t)img << 18);  // 1024*256 float4/image
  f4_t* __restrict__ ob = out + ((size_t)img << 18);

  const f4_t zero = {0.f, 0.f, 0.f, 0.f};
  // History prologue: rows r0-2, r0-1 (zero if out of image).
  f4_t s_m2 = (r0 >= 2) ? xb[(r0 - 2) * W4 + c] : zero;
  f4_t s_m1 = (r0 >= 1) ? xb[(r0 - 1) * W4 + c] : zero;

  int idx = r0 * W4 + c;
#pragma unroll 8
  for (int r = 0; r < ROWS; ++r, idx += W4) {
    f4_t a = xb[idx];
    f4_t o = a - s_m2;
    __builtin_nontemporal_store(o, &ob[idx]);
    s_m2 = s_m1;
    s_m1 = a;
  }
}

extern "C" void kernel_launch(void* const* d_in, const int* in_sizes, int n_in,
                              void* d_out, int out_size, void* d_ws, size_t ws_size,
                              hipStream_t stream) {
  const f4_t* x = (const f4_t*)d_in[0];
  f4_t* out = (f4_t*)d_out;
  // 32 images * (1024 rows / 32 rows-per-block) = 1024 blocks
  dir2_diff_kernel<<<1024, 256, 0, stream>>>(x, out);
}

// Round 6
// 45.417 us; speedup vs baseline: 1.0328x; 1.0038x over previous
//
#include <hip/hip_runtime.h>

// out[b, r, c] = x[b, r, c] - (r >= 2 ? x[b, r-2, c] : 0)
// x: (32, 1, 1024, 1024) float32.
//
// Register-history + batched loads: each block owns a 32-row strip of one
// image (256 threads = 256 float4 columns). The strip is processed in
// batches of 8 rows: all 8 loads are issued back-to-back into a statically
// indexed register array (8 outstanding global_load_dwordx4 per wave ->
// high memory-level parallelism), then the 8 diffs are computed and stored.
// Previous version (VGPR=28) serialized load->sub->store per row with
// vmcnt(0) waits, capping effective HBM BW at ~4.5 TB/s.

typedef float f4_t __attribute__((ext_vector_type(4)));

__global__ __launch_bounds__(256) void dir2_diff_kernel(
    const f4_t* __restrict__ x, f4_t* __restrict__ out) {
  constexpr int W4 = 256;    // float4s per row
  constexpr int ROWS = 32;   // rows per block strip
  constexpr int BATCH = 8;   // rows loaded before any store

  const int img = blockIdx.x >> 5;    // 32 chunks per image
  const int chunk = blockIdx.x & 31;
  const int r0 = chunk * ROWS;
  const int c = threadIdx.x;

  const f4_t* __restrict__ xb = x + ((size_t)img << 18);  // 1024*256 float4/image
  f4_t* __restrict__ ob = out + ((size_t)img << 18);

  const f4_t zero = {0.f, 0.f, 0.f, 0.f};
  // History prologue: rows r0-2, r0-1 (zero if out of image).
  f4_t s_m2 = (r0 >= 2) ? xb[(r0 - 2) * W4 + c] : zero;
  f4_t s_m1 = (r0 >= 1) ? xb[(r0 - 1) * W4 + c] : zero;

  int idx = r0 * W4 + c;
  for (int b = 0; b < ROWS / BATCH; ++b) {
    f4_t a[BATCH];
    // Issue all BATCH loads before any use (static indices -> registers).
#pragma unroll
    for (int j = 0; j < BATCH; ++j) {
      a[j] = xb[idx + j * W4];
    }
    // Compute diffs and store; history carries across the batch.
#pragma unroll
    for (int j = 0; j < BATCH; ++j) {
      f4_t o = a[j] - s_m2;
      __builtin_nontemporal_store(o, &ob[idx + j * W4]);
      s_m2 = s_m1;
      s_m1 = a[j];
    }
    idx += BATCH * W4;
  }
}

extern "C" void kernel_launch(void* const* d_in, const int* in_sizes, int n_in,
                              void* d_out, int out_size, void* d_ws, size_t ws_size,
                              hipStream_t stream) {
  const f4_t* x = (const f4_t*)d_in[0];
  f4_t* out = (f4_t*)d_out;
  // 32 images * (1024 rows / 32 rows-per-block) = 1024 blocks
  dir2_diff_kernel<<<1024, 256, 0, stream>>>(x, out);
}